// Round 16
// baseline (76.365 us; speedup 1.0000x reference)
//
#include <hip/hip_runtime.h>
#include <stdint.h>

#define ALPHA 0.2f
#define LOG2E 1.44269504089f

typedef __attribute__((ext_vector_type(8))) short s16x8;
typedef __attribute__((ext_vector_type(4))) float f32x4;
typedef __attribute__((ext_vector_type(4))) unsigned u32x4;

__device__ __forceinline__ unsigned short f2bf(float f) {
    union { float f; unsigned u; } c; c.f = f;
    unsigned u = c.u;
    u += 0x7fffu + ((u >> 16) & 1u);
    return (unsigned short)(u >> 16);
}

// ---- prep: wT bf16 [c=256][f=256] (c=(h,e)) + wa1/wa2 = log2e * W@a{1,2} ----
__global__ void k_prep_w(const float* __restrict__ weight, const float* __restrict__ att,
                         unsigned short* __restrict__ wT, float* __restrict__ wa1,
                         float* __restrict__ wa2) {
    int blk = blockIdx.x, t = threadIdx.x;
    if (blk < 256) {
        int c = blk, h = c >> 5, e = c & 31;
        wT[c * 256 + t] = f2bf(weight[h * 8192 + t * 32 + e]);
    } else {
        int id = blk - 256, h = id >> 1, which = id & 1;
        float s = 0.f;
        for (int e = 0; e < 32; ++e)
            s += weight[h * 8192 + t * 32 + e] * att[h * 64 + which * 32 + e];
        s *= LOG2E;   // scores in log2 domain (leaky commutes with positive scale)
        (which ? wa2 : wa1)[h * 256 + t] = s;
    }
}

// ---- fused: adj->gmask ballots, x->LDS, s1/s2 dots, AND Wh^T MFMA (r15-proven) ----
__global__ void __launch_bounds__(512) k_pre(const int* __restrict__ adj,
                                             unsigned* __restrict__ gmask,
                                             const float* __restrict__ x,
                                             const unsigned short* __restrict__ wT,
                                             const float* __restrict__ wa1,
                                             const float* __restrict__ wa2,
                                             float* __restrict__ s1,
                                             float* __restrict__ s2,
                                             unsigned short* __restrict__ WhT) {
    __shared__ unsigned char adjb[16][1024];   // 0/1 bytes, col ^ ((row&7)<<4) swizzle
    __shared__ float xs[16][260];
    __shared__ unsigned short x16s[16][256];   // bf16 rows, 16B-unit XOR swizzle
    int blk = blockIdx.x;                      // blk = b*64 + mt
    int t = threadIdx.x, w = t >> 6, l = t & 63;
    int b = blk >> 6;
    const int* abase = adj + blk * 16384;
#pragma unroll
    for (int it = 0; it < 8; ++it) {
        int f = it * 512 + t;
        int4 v = *(const int4*)(abase + f * 4);
        int row = f >> 8, col = (f & 255) * 4;
        unsigned p1 = __builtin_amdgcn_perm((unsigned)v.y, (unsigned)v.x, 0x00000400u);
        unsigned p2 = __builtin_amdgcn_perm((unsigned)v.w, (unsigned)v.z, 0x00000400u);
        unsigned pk = __builtin_amdgcn_perm(p2, p1, 0x05040100u);
        *(unsigned*)&adjb[row][col ^ ((row & 7) << 4)] = pk;
    }
    const float* xbase = x + blk * 4096;
#pragma unroll
    for (int it = 0; it < 2; ++it) {
        int f = it * 512 + t;
        float4 xv = *(const float4*)(xbase + f * 4);
        int row = f >> 6, col = (f & 63) * 4;
        *(float4*)&xs[row][col] = xv;
        ushort4 hv;
        hv.x = f2bf(xv.x); hv.y = f2bf(xv.y); hv.z = f2bf(xv.z); hv.w = f2bf(xv.w);
        *(ushort4*)((char*)&x16s[0][0] + ((row * 512 + col * 2) ^ ((row & 7) << 4))) = hv;
    }
    __syncthreads();
    if (w < 4) {
        for (int k = 0; k < 64; ++k) {
            int task = w * 64 + k;
            int row = task >> 4, ch = task & 15;
            unsigned char byv = adjb[row][(ch * 64 + l) ^ ((row & 7) << 4)];
            unsigned long long mk = __ballot(byv != 0);
            if (l == 0) {
                unsigned* dst = gmask + (blk * 16 + row) * 32 + ch * 2;
                dst[0] = (unsigned)mk;
                dst[1] = (unsigned)(mk >> 32);
            }
        }
    } else {
        int td = (w - 4) * 64 + l;
        int row = td & 15, grp = td >> 4;
        int h = grp >> 1, which = grp & 1;
        const float* wap = (which ? wa2 : wa1) + h * 256;
        float s = 0.f;
#pragma unroll 4
        for (int f = 0; f < 256; f += 4) {
            f32x4 xv = *(const f32x4*)&xs[row][f];
            f32x4 wv = *(const f32x4*)&wap[f];
            s += xv[0] * wv[0] + xv[1] * wv[1] + xv[2] * wv[2] + xv[3] * wv[3];
        }
        int m = (blk & 63) * 16 + row;
        (which ? s2 : s1)[(b * 8 + h) * 1024 + m] = s;
    }
    int lrow = l & 15, lk = l >> 4;
#pragma unroll
    for (int ct = 0; ct < 2; ++ct) {
        int c0 = (w * 2 + ct) * 16;
        f32x4 acc = {0, 0, 0, 0};
        const unsigned short* ap = wT + (c0 + lrow) * 256 + lk * 8;
#pragma unroll
        for (int k0 = 0; k0 < 256; k0 += 32) {
            s16x8 af = *(const s16x8*)(ap + k0);
            s16x8 bf = *(const s16x8*)((char*)&x16s[0][0] +
                        ((lrow * 512 + (lk * 8 + k0) * 2) ^ ((lrow & 7) << 4)));
            acc = __builtin_amdgcn_mfma_f32_16x16x32_bf16(af, bf, acc, 0, 0, 0);
        }
#pragma unroll
        for (int j = 0; j < 4; ++j) {
            int c = c0 + lk * 4 + j;
            WhT[(b * 256 + c) * 1024 + (blk & 63) * 16 + lrow] = f2bf(acc[j]);
        }
    }
}

// ---- top-16 of s2 per (b,h): sorted desc values + indices ----
__global__ void __launch_bounds__(64) k_top(const float* __restrict__ s2,
                                            float* __restrict__ tval,
                                            unsigned* __restrict__ tidx) {
    int bh = blockIdx.x, l = threadIdx.x;
    const float* p = s2 + bh * 1024;
    float v[16];
#pragma unroll
    for (int k = 0; k < 4; ++k) {
        f32x4 x4 = *(const f32x4*)(p + l * 16 + k * 4);
        v[k * 4 + 0] = x4[0]; v[k * 4 + 1] = x4[1];
        v[k * 4 + 2] = x4[2]; v[k * 4 + 3] = x4[3];
    }
    unsigned used = 0;
    for (int r = 0; r < 16; ++r) {
        float lmax = -3.0e38f; int larg = 0;
#pragma unroll
        for (int k = 0; k < 16; ++k) {
            float c = ((used >> k) & 1u) ? -3.0e38f : v[k];
            if (c > lmax) { lmax = c; larg = k; }
        }
        float wmax = lmax;
#pragma unroll
        for (int off = 32; off >= 1; off >>= 1) wmax = fmaxf(wmax, __shfl_xor(wmax, off));
        unsigned long long hm = __ballot(lmax == wmax);
        int fl = (int)__builtin_ctzll(hm);
        if (l == fl) {
            tval[bh * 16 + r] = wmax;
            tidx[bh * 16 + r] = (unsigned)(l * 16 + larg);
            used |= 1u << larg;
        }
    }
}

// ---- attention: top-16-probe row max (O(16)/row, exact w.h.p., safe on miss)
//      + r15 pass B; no pass-A sweep, no mxsh barrier ----
__global__ void __launch_bounds__(512, 4) k_attn(const unsigned* __restrict__ gmask,
                                                 const float* __restrict__ s1,
                                                 const float* __restrict__ s2,
                                                 const float* __restrict__ tval,
                                                 const unsigned* __restrict__ tidx,
                                                 const unsigned short* __restrict__ WhT,
                                                 float* __restrict__ out) {
    __shared__ float s2s[4][1024];
    __shared__ unsigned amaskw[16][36];
    __shared__ float s1s[4][16];
    __shared__ float accsh[4][64][13];
    int bid = blockIdx.x;
    int o = (bid & 7) * 128 + (bid >> 3);   // XCD swizzle: each XCD owns one b
    int b = o >> 7, r = o & 127;
    int mt = r >> 1, m0 = mt * 16, hg = (r & 1) * 4;
    int t = threadIdx.x, w = t >> 6, l = t & 63;
    int hd = w & 3, nh = w >> 2;
    for (int i = t; i < 4096; i += 512)
        s2s[i >> 10][i & 1023] = s2[b * 8192 + hg * 1024 + i];
    amaskw[t >> 5][t & 31] = gmask[(b * 1024 + m0) * 32 + t];
    if (t < 64) s1s[t >> 4][t & 15] = s1[b * 8192 + (hg + (t >> 4)) * 1024 + m0 + (t & 15)];
    __syncthreads();
    int m = l & 15, q = l >> 4;
    int h = hg + hd;
    int nbase = nh * 512;
    // ---- pass A': probe top-16 sorted ranks; first masked-in rank = EXACT
    //      masked row max; miss (P=2^-16) falls back to val[15] (upper bound,
    //      within ~10 log2 of true max -> still safe & shift-invariant) ----
    const float*    tv = tval + (b * 8 + h) * 16;
    const unsigned* ti = tidx + (b * 8 + h) * 16;
    float mxs2 = tv[15];
#pragma unroll
    for (int j = 0; j < 16; ++j) {
        unsigned id = ti[j];
        unsigned wd = amaskw[m][id >> 5];
        unsigned bit = (wd >> (id & 31u)) & 1u;
        mxs2 = fmaxf(mxs2, bit ? tv[j] : -3.0e38f);
    }
    float s1v = s1s[hd][m];
    float mxr = s1v + mxs2;
    float mx = fmaxf(mxr, ALPHA * mxr);   // >= leaky(any masked score): safe shift
    float cc1 = s1v - mx;
    float cc2 = fmaf(ALPHA, s1v, -mx);
    u32x4 mv0 = *(const u32x4*)&amaskw[m][nh * 16];
    u32x4 mv1 = *(const u32x4*)&amaskw[m][nh * 16 + 4];
    u32x4 mv2 = *(const u32x4*)&amaskw[m][nh * 16 + 8];
    u32x4 mv3 = *(const u32x4*)&amaskw[m][nh * 16 + 12];
    // ---- pass B: arg = bit ? leaky(score)-mx : -3e38 (select BEFORE exp) ----
    f32x4 acc0 = {0,0,0,0}, acc1 = {0,0,0,0}, accs = {0,0,0,0};
    s16x8 ones;
#pragma unroll
    for (int u = 0; u < 8; ++u) ones[u] = (short)0x3F80;   // bf16 1.0
    const unsigned short* bp0 = WhT + (b * 8 + h) * 32768 + m * 1024 + q * 8 + nbase;
    const unsigned short* bp1 = bp0 + 16 * 1024;
#pragma unroll
    for (int i = 0; i < 16; ++i) {
        int n0 = i * 32;
        unsigned word = (i < 4 ? mv0[i & 3] : i < 8 ? mv1[i & 3] : i < 12 ? mv2[i & 3]
                                                                          : mv3[i & 3]);
        unsigned wm8 = word >> (q * 8);
        int nn = nbase + n0 + q * 8;
        f32x4 svA = *(const f32x4*)&s2s[hd][nn];
        f32x4 svB = *(const f32x4*)&s2s[hd][nn + 4];
        float pv[8];
#pragma unroll
        for (int u = 0; u < 8; ++u) {
            float sv = (u < 4 ? svA[u] : svB[u - 4]);
            float arg = fmaxf(sv + cc1, fmaf(ALPHA, sv, cc2));   // leaky(score)-mx
            arg = ((wm8 >> u) & 1u) ? arg : -3.0e38f;            // select BEFORE exp
            pv[u] = __builtin_amdgcn_exp2f(arg);
        }
        u32x4 aw;
#pragma unroll
        for (int p = 0; p < 4; ++p) {
            union { float f; unsigned u; } lo, hi;
            lo.f = pv[2 * p]; hi.f = pv[2 * p + 1];
            aw[p] = __builtin_amdgcn_perm(hi.u, lo.u, 0x07060302u);  // trunc-pack 2xbf16
        }
        s16x8 af = __builtin_bit_cast(s16x8, aw);
        s16x8 bf0 = *(const s16x8*)(bp0 + n0);
        s16x8 bf1 = *(const s16x8*)(bp1 + n0);
        acc0 = __builtin_amdgcn_mfma_f32_16x16x32_bf16(af, bf0, acc0, 0, 0, 0);
        acc1 = __builtin_amdgcn_mfma_f32_16x16x32_bf16(af, bf1, acc1, 0, 0, 0);
        accs = __builtin_amdgcn_mfma_f32_16x16x32_bf16(af, ones, accs, 0, 0, 0);
    }
    if (nh == 1) {
#pragma unroll
        for (int j = 0; j < 4; ++j) {
            accsh[hd][l][j]     = acc0[j];
            accsh[hd][l][4 + j] = acc1[j];
            accsh[hd][l][8 + j] = accs[j];
        }
    }
    __syncthreads();
    if (nh == 0) {
#pragma unroll
        for (int j = 0; j < 4; ++j) {
            float a0 = acc0[j] + accsh[hd][l][j];      // identical mx both halves
            float a1 = acc1[j] + accsh[hd][l][4 + j];
            float as = accs[j] + accsh[hd][l][8 + j];
            float inv = 1.f / as;
            float v0 = a0 * inv;
            float v1 = a1 * inv;
            v0 = v0 > 0.f ? v0 : __expf(v0) - 1.f;
            v1 = v1 > 0.f ? v1 : __expf(v1) - 1.f;
            int mrow = q * 4 + j;
            float* op = &out[(b * 1024 + m0 + mrow) * 256 + h * 32];
            op[m] = v0;
            op[16 + m] = v1;
        }
    }
}

extern "C" void kernel_launch(void* const* d_in, const int* in_sizes, int n_in,
                              void* d_out, int out_size, void* d_ws, size_t ws_size,
                              hipStream_t stream) {
    const float* x      = (const float*)d_in[0];
    const int*   adj    = (const int*)d_in[1];
    const float* weight = (const float*)d_in[2];
    const float* att    = (const float*)d_in[3];

    char* ws = (char*)d_ws;
    unsigned short* wT  = (unsigned short*)(ws);             // 128K
    unsigned short* WhT = (unsigned short*)(ws + 131072);    // 4M
    float* s1  = (float*)(ws + 4325376);                     // 256K
    float* s2  = (float*)(ws + 4587520);                     // 256K
    float* wa1 = (float*)(ws + 4849664);                     // 8K
    float* wa2 = (float*)(ws + 4857856);                     // 8K
    unsigned* gmask = (unsigned*)(ws + 4866048);             // 1M
    float*    tval  = (float*)(ws + 5914624);                // 4K
    unsigned* tidx  = (unsigned*)(ws + 5918720);             // 4K (end ~5.92MB)
    float* out = (float*)d_out;

    k_prep_w<<<272, 256, 0, stream>>>(weight, att, wT, wa1, wa2);
    k_pre<<<512, 512, 0, stream>>>(adj, gmask, x, wT, wa1, wa2, s1, s2, WhT);
    k_top<<<64, 64, 0, stream>>>(s2, tval, tidx);
    k_attn<<<1024, 512, 0, stream>>>(gmask, s1, s2, tval, tidx, WhT, out);
}